// Round 9
// baseline (522.878 us; speedup 1.0000x reference)
//
#include <hip/hip_runtime.h>

#define NN 100000
#define NE 1600000

typedef __attribute__((ext_vector_type(8))) short short8;   // 8 bf16 = 4 VGPRs (MFMA A/B frag)
typedef __attribute__((ext_vector_type(4))) float f32x4;    // MFMA C/D frag

// bf16 helpers
static __device__ __forceinline__ unsigned f2bf_rne(float f) {
    unsigned u = __float_as_uint(f);
    return (u + 0x7FFFu + ((u >> 16) & 1u)) >> 16;   // round-to-nearest-even
}
static __device__ __forceinline__ float bf_lo(unsigned u) { return __uint_as_float(u << 16); }
static __device__ __forceinline__ float bf_hi(unsigned u) { return __uint_as_float(u & 0xFFFF0000u); }

// packed[]: DENSE u64 per node. count in bits 0..23, sum(ew*2^20) in 24..63.
// Aliases meta's storage (packed dead after k_scan1; meta written by k_fill).
// fused: k_init (zero packed) + 3x k_prep (W -> W^T bf16 hi/lo) in one launch.
__global__ __launch_bounds__(256) void k_pre(unsigned long long* packed, int n,
                                             const float* __restrict__ W1,
                                             const float* __restrict__ W2,
                                             const float* __restrict__ W3,
                                             ushort* __restrict__ wt) {
    int b = blockIdx.x;
    int t = threadIdx.x;
    if (b < 391) {
        int i = b * 256 + t;
        if (i < n) packed[i] = 0ull;
        return;
    }
    int pb = b - 391;                    // 0..191
    int wsel = pb >> 6;                  // 0,1,2
    const float* W = (wsel == 0) ? W1 : (wsel == 1) ? W2 : W3;
    ushort* Wth = wt + wsel * 2 * 16384;
    ushort* Wtl = Wth + 16384;
    int idx = (pb & 63) * 256 + t;       // 0..16383
    int k = idx >> 7, nn = idx & 127;
    float w = W[idx];
    unsigned hi = f2bf_rne(w);
    unsigned lo = f2bf_rne(w - bf_lo(hi));   // residual: W ~= hi + lo to ~2^-17 rel
    Wth[nn * 128 + k] = (ushort)hi;
    Wtl[nn * 128 + k] = (ushort)lo;
}

// ---------------- MFMA GEMM core: 32 rows x 128 cols per block, 4 waves ----------------
template <bool SPLIT_A>
static __device__ __forceinline__ void mfma_tile(const ushort* sAh, const ushort* sAl,
                                                 const ushort* __restrict__ Wth,
                                                 const ushort* __restrict__ Wtl,
                                                 unsigned* __restrict__ Cb,
                                                 size_t r0, int t) {
    int w  = t >> 6;
    int l  = t & 63;
    int lr = l & 15;            // row idx within A-frag / col idx within B-frag
    int lk = (l >> 4) << 3;     // k offset 0,8,16,24 within the 32-wide k-step
    int n0 = w * 32;

    short8 bh[2][4], bl[2][4];
#pragma unroll
    for (int cf = 0; cf < 2; ++cf)
#pragma unroll
        for (int ks = 0; ks < 4; ++ks) {
            int n = n0 + cf * 16 + lr;
            bh[cf][ks] = *(const short8*)&Wth[n * 128 + ks * 32 + lk];
            bl[cf][ks] = *(const short8*)&Wtl[n * 128 + ks * 32 + lk];
        }

    f32x4 zero = {0.f, 0.f, 0.f, 0.f};
    f32x4 acc[2][2] = {{zero, zero}, {zero, zero}};

    __syncthreads();   // sA staging (done by caller) now visible

#pragma unroll
    for (int ks = 0; ks < 4; ++ks) {
        short8 ah[2], al[2];
#pragma unroll
        for (int rf = 0; rf < 2; ++rf) {
            int off = (rf * 16 + lr) * 136 + ks * 32 + lk;
            ah[rf] = *(const short8*)&sAh[off];
            if (SPLIT_A) al[rf] = *(const short8*)&sAl[off];
        }
#pragma unroll
        for (int rf = 0; rf < 2; ++rf)
#pragma unroll
            for (int cf = 0; cf < 2; ++cf) {
                acc[rf][cf] = __builtin_amdgcn_mfma_f32_16x16x32_bf16(ah[rf], bh[cf][ks], acc[rf][cf], 0, 0, 0);
                acc[rf][cf] = __builtin_amdgcn_mfma_f32_16x16x32_bf16(ah[rf], bl[cf][ks], acc[rf][cf], 0, 0, 0);
                if (SPLIT_A)
                    acc[rf][cf] = __builtin_amdgcn_mfma_f32_16x16x32_bf16(al[rf], bh[cf][ks], acc[rf][cf], 0, 0, 0);
            }
    }

    // C/D layout: col = l&15, row = (l>>4)*4 + reg. Pack bf16 col-pairs via shfl_xor(1).
#pragma unroll
    for (int rf = 0; rf < 2; ++rf)
#pragma unroll
        for (int cf = 0; cf < 2; ++cf)
#pragma unroll
            for (int r = 0; r < 4; ++r) {
                unsigned b = f2bf_rne(acc[rf][cf][r]);
                unsigned p = (unsigned)__shfl_xor((int)b, 1);
                if (!(l & 1)) {
                    size_t row = r0 + rf * 16 + ((l >> 4) << 2) + r;
                    int c = n0 + cf * 16 + lr;           // even
                    Cb[(row * 128 + c) >> 1] = b | (p << 16);
                }
            }
}

// ---------------- fused: layer-1 MFMA GEMM (fp32 A, split) || edge histogram ----------------
__global__ __launch_bounds__(256) void k_gp(const float* __restrict__ A,
                                            const ushort* __restrict__ Wth,
                                            const ushort* __restrict__ Wtl,
                                            unsigned* __restrict__ Cb,
                                            const int* __restrict__ col,
                                            const float* __restrict__ ew,
                                            unsigned long long* packed,
                                            int* __restrict__ rank, int e) {
    __shared__ alignas(16) ushort sAh[32 * 136];
    __shared__ alignas(16) ushort sAl[32 * 136];
    int b = blockIdx.x;
    int sub = b % 3;
    int q = b / 3;
    int t = threadIdx.x;

    if (sub != 0) {
        int p = q * 2 + sub - 1;            // 0..6249
        int i = p * 256 + t;
        if (i < e) {
            int c = col[i];
            unsigned fe = (unsigned)__float2uint_rn(ew[i] * 1048576.0f);  // 20 frac bits
            unsigned long long inc = ((unsigned long long)fe << 24) | 1ull;
            unsigned long long old = atomicAdd(&packed[c], inc);
            rank[i] = (int)(old & 0xFFFFFFull);
        }
        return;
    }

    size_t r0 = (size_t)q * 32;
    const float4* A4 = (const float4*)(A + r0 * 128);
#pragma unroll
    for (int i = 0; i < 4; ++i) {
        int j = t + 256 * i;                // float4 idx 0..1023
        float4 f = A4[j];
        int rr = j >> 5;
        int cc = (j & 31) << 2;
        unsigned h0 = f2bf_rne(f.x), h1 = f2bf_rne(f.y), h2 = f2bf_rne(f.z), h3 = f2bf_rne(f.w);
        unsigned g0 = f2bf_rne(f.x - bf_lo(h0)), g1 = f2bf_rne(f.y - bf_lo(h1));
        unsigned g2 = f2bf_rne(f.z - bf_lo(h2)), g3 = f2bf_rne(f.w - bf_lo(h3));
        *(ushort4*)&sAh[rr * 136 + cc] = make_ushort4((ushort)h0, (ushort)h1, (ushort)h2, (ushort)h3);
        *(ushort4*)&sAl[rr * 136 + cc] = make_ushort4((ushort)g0, (ushort)g1, (ushort)g2, (ushort)g3);
    }
    mfma_tile<true>(sAh, sAl, Wth, Wtl, Cb, r0, t);
}

// fused: exclusive scan of counts -> rowptr (RAW, block-local), block sums, dinv
__global__ __launch_bounds__(256) void k_scan1(const unsigned long long* __restrict__ packed,
                                               int* __restrict__ rowptr,
                                               int* __restrict__ part,
                                               float* __restrict__ dinv, int n) {
    __shared__ int s[256];
    int t = threadIdx.x;
    int i = blockIdx.x * 256 + t;
    unsigned long long pk = (i < n) ? packed[i] : 0ull;
    int v = (int)(pk & 0xFFFFFFull);
    if (i < n) {
        float deg = 1.0f + (float)(pk >> 24) * (1.0f / 1048576.0f);  // +1 self-loop
        dinv[i] = rsqrtf(deg);
    }
    s[t] = v;
    __syncthreads();
    for (int d = 1; d < 256; d <<= 1) {
        int y = (t >= d) ? s[t - d] : 0;
        __syncthreads();
        s[t] += y;
        __syncthreads();
    }
    if (i < n) rowptr[i] = s[t] - v;
    if (t == 255) part[blockIdx.x] = s[255];
}

// scan of block sums -> part (exclusive); also patch rowptr[NN] so that
// rowptr[NN] + part[NN>>8] == e (consumers fold part at read time; scan3 gone).
__global__ __launch_bounds__(512) void k_scan2(int* part, int m, int* rowptr, int e) {
    __shared__ int s[512];
    int t = threadIdx.x;
    int v = (t < m) ? part[t] : 0;
    s[t] = v;
    __syncthreads();
    for (int d = 1; d < 512; d <<= 1) {
        int y = (t >= d) ? s[t - d] : 0;
        __syncthreads();
        s[t] += y;
        __syncthreads();
    }
    if (t < m) part[t] = s[t] - v;
    if (t == m - 1) rowptr[NN] = e - (s[t] - v);
}

// atomic-free CSR fill (part folded); one 8-byte scattered store per edge
__global__ __launch_bounds__(256) void k_fill(const int* __restrict__ row,
                                              const int* __restrict__ col,
                                              const float* __restrict__ ew,
                                              const int* __restrict__ rowptr,
                                              const int* __restrict__ part,
                                              const int* __restrict__ rank,
                                              const float* __restrict__ dinv,
                                              uint2* __restrict__ meta, int e) {
    int i = blockIdx.x * 256 + threadIdx.x;
    if (i < e) {
        int c = col[i];
        int r = row[i];
        int p = rowptr[c] + part[c >> 8] + rank[i];
        float w = dinv[r] * ew[i] * dinv[c];
        meta[p] = make_uint2((unsigned)r, __float_as_uint(w));
    }
}

// ---------------- QUAD-node aggregation core (per half-wave) ----------------
// Half-wave h owns 4 nodes of SIMILAR degree (degree-sorted grouping by caller);
// lane owns feature quad q. 4 chunk-meta loads + 16 gathers in flight.
// Each node's accumulation is strictly sequential in its CSR order per feature:
// bit-identical association to the verified r6/r7/r8 versions.
static __device__ __forceinline__ void agg_quad(const uint2* __restrict__ X2,
                                                const uint2* __restrict__ meta,
                                                const float* __restrict__ dinv,
                                                float4 bv, int h, int q,
                                                const int* node, const int* p0,
                                                const int* deg, float acc[4][4]) {
#pragma unroll
    for (int X = 0; X < 4; ++X) {
        float di = dinv[node[X]];
        float sw = di * di;
        uint2 us = X2[(size_t)node[X] * 32 + q];
        acc[X][0] = fmaf(sw, bf_lo(us.x), bv.x);
        acc[X][1] = fmaf(sw, bf_hi(us.x), bv.y);
        acc[X][2] = fmaf(sw, bf_lo(us.y), bv.z);
        acc[X][3] = fmaf(sw, bf_hi(us.y), bv.w);
    }
    int dloc = max(max(deg[0], deg[1]), max(deg[2], deg[3]));

    for (int base = 0; base < dloc; base += 32) {
        int m[4], idx[4];
#pragma unroll
        for (int X = 0; X < 4; ++X) {
            int mx = deg[X] - base;
            m[X] = mx > 32 ? 32 : mx;
            int ix = p0[X] + base + (q < m[X] ? q : (m[X] > 0 ? m[X] - 1 : 0));
            if (m[X] <= 0) ix = p0[X];
            if (ix > NE - 1) ix = NE - 1;
            idx[X] = ix;
        }
        int sv[4]; float wv[4];
#pragma unroll
        for (int X = 0; X < 4; ++X) {
            uint2 mv = meta[idx[X]];
            sv[X] = (int)mv.x;
            wv[X] = __uint_as_float(mv.y);
        }
        int mmax = dloc - base;  mmax = mmax > 32 ? 32 : mmax;

        int j = 0;
        for (; j + 4 <= mmax; j += 4) {
#pragma unroll
            for (int u = 0; u < 4; ++u) {
                int jj = j + u;
#pragma unroll
                for (int X = 0; X < 4; ++X) {
                    int s = __shfl(sv[X], (h << 5) | jj);
                    float w = __shfl(wv[X], (h << 5) | jj);
                    w = (jj < m[X]) ? w : 0.0f;
                    uint2 ux = X2[(size_t)s * 32 + q];
                    acc[X][0] = fmaf(w, bf_lo(ux.x), acc[X][0]);
                    acc[X][1] = fmaf(w, bf_hi(ux.x), acc[X][1]);
                    acc[X][2] = fmaf(w, bf_lo(ux.y), acc[X][2]);
                    acc[X][3] = fmaf(w, bf_hi(ux.y), acc[X][3]);
                }
            }
        }
        for (; j < mmax; ++j) {
#pragma unroll
            for (int X = 0; X < 4; ++X) {
                int s = __shfl(sv[X], (h << 5) | j);
                float w = __shfl(wv[X], (h << 5) | j);
                w = (j < m[X]) ? w : 0.0f;
                uint2 ux = X2[(size_t)s * 32 + q];
                acc[X][0] = fmaf(w, bf_lo(ux.x), acc[X][0]);
                acc[X][1] = fmaf(w, bf_hi(ux.x), acc[X][1]);
                acc[X][2] = fmaf(w, bf_lo(ux.y), acc[X][2]);
                acc[X][3] = fmaf(w, bf_hi(ux.y), acc[X][3]);
            }
        }
    }
}

// Degree-sort the block's 32 nodes (bitonic, LDS) and hand each half-wave a run
// of 4 similar-degree slots. skey = (deg<<5)|ln. Returns node/p0/deg arrays.
static __device__ __forceinline__ void sort_and_assign(const int* __restrict__ rowptr,
                                                       const int* __restrict__ part,
                                                       size_t r0, int t, int g,
                                                       int* skey,
                                                       int* node, int* p0, int* deg, int* ln) {
    if (t < 32) {
        int i = (int)r0 + t;
        int pa = rowptr[i] + part[i >> 8];
        int pb = rowptr[i + 1] + part[(i + 1) >> 8];
        skey[t] = ((pb - pa) << 5) | t;
    }
    __syncthreads();
    for (int k = 2; k <= 32; k <<= 1) {
        for (int s = k >> 1; s > 0; s >>= 1) {
            if (t < 32) {
                int ixj = t ^ s;
                if (ixj > t) {
                    int a = skey[t], b = skey[ixj];
                    bool asc = ((t & k) == 0);
                    if (asc ? (a > b) : (a < b)) { skey[t] = b; skey[ixj] = a; }
                }
            }
            __syncthreads();
        }
    }
#pragma unroll
    for (int s = 0; s < 4; ++s) {
        int key = skey[g * 4 + s];
        ln[s] = key & 31;
        deg[s] = key >> 5;
        int i = (int)r0 + ln[s];
        node[s] = i;
        p0[s] = rowptr[i] + part[i >> 8];
    }
}

// ---------------- fused: aggregation(layer L) + relu/bias + GEMM(layer L+1) ----------------
// Block owns 32 nodes: 8 half-waves x 4 nodes (degree-sorted groups), one pass.
__global__ __launch_bounds__(256) void k_aggemm(const unsigned* __restrict__ Xsrc,
                                                const int* __restrict__ rowptr,
                                                const int* __restrict__ part,
                                                const uint2* __restrict__ meta,
                                                const float* __restrict__ dinv,
                                                const float* __restrict__ bias,
                                                const ushort* __restrict__ Wth,
                                                const ushort* __restrict__ Wtl,
                                                unsigned* __restrict__ Cb) {
    __shared__ alignas(16) ushort sA[32 * 136];
    __shared__ int skey[32];
    int t = threadIdx.x;
    int lane = t & 63, wid = t >> 6;
    int h = lane >> 5, q = lane & 31;
    int g = (wid << 1) | h;
    const uint2* X2 = (const uint2*)Xsrc;
    size_t r0 = (size_t)blockIdx.x * 32;

    int node[4], p0[4], deg[4], ln[4];
    sort_and_assign(rowptr, part, r0, t, g, skey, node, p0, deg, ln);

    float4 bv = *(const float4*)(bias + q * 4);
    float acc[4][4];
    agg_quad(X2, meta, dinv, bv, h, q, node, p0, deg, acc);

#pragma unroll
    for (int X = 0; X < 4; ++X) {
        float a0 = fmaxf(acc[X][0], 0.0f), a1 = fmaxf(acc[X][1], 0.0f);
        float a2 = fmaxf(acc[X][2], 0.0f), a3 = fmaxf(acc[X][3], 0.0f);
        *(ushort4*)&sA[ln[X] * 136 + (q << 2)] =
            make_ushort4((ushort)f2bf_rne(a0), (ushort)f2bf_rne(a1),
                         (ushort)f2bf_rne(a2), (ushort)f2bf_rne(a3));
    }
    mfma_tile<false>(sA, nullptr, Wth, Wtl, Cb, r0, t);
}

// ---------------- standalone aggregation for layer 3 (fp32 out, no relu) ----------------
// Block owns 32 nodes, degree-sorted quad groups; grid 3125.
__global__ __launch_bounds__(256) void k_agg(const unsigned* __restrict__ XWb,
                                             const int* __restrict__ rowptr,
                                             const int* __restrict__ part,
                                             const uint2* __restrict__ meta,
                                             const float* __restrict__ dinv,
                                             const float* __restrict__ bias,
                                             float* __restrict__ outf) {
    __shared__ int skey[32];
    int t = threadIdx.x;
    int lane = t & 63, wid = t >> 6;
    int h = lane >> 5, q = lane & 31;
    int g = (wid << 1) | h;
    size_t r0 = (size_t)blockIdx.x * 32;

    int node[4], p0[4], deg[4], ln[4];
    sort_and_assign(rowptr, part, r0, t, g, skey, node, p0, deg, ln);

    float4 bv = *(const float4*)(bias + q * 4);
    float acc[4][4];
    agg_quad((const uint2*)XWb, meta, dinv, bv, h, q, node, p0, deg, acc);

#pragma unroll
    for (int X = 0; X < 4; ++X)
        *(float4*)(outf + (size_t)node[X] * 128 + q * 4) =
            make_float4(acc[X][0], acc[X][1], acc[X][2], acc[X][3]);
}

// ---------------- launcher ----------------
extern "C" void kernel_launch(void* const* d_in, const int* in_sizes, int n_in,
                              void* d_out, int out_size, void* d_ws, size_t ws_size,
                              hipStream_t stream) {
    const float* x  = (const float*)d_in[0];
    const int*   ei = (const int*)d_in[1];
    const float* ew = (const float*)d_in[2];
    const float* W1 = (const float*)d_in[3];
    const float* b1 = (const float*)d_in[4];
    const float* W2 = (const float*)d_in[5];
    const float* b2 = (const float*)d_in[6];
    const float* W3 = (const float*)d_in[7];
    const float* b3 = (const float*)d_in[8];
    float* out = (float*)d_out;

    const int n = NN, e = NE;
    const int* row = ei;
    const int* col = ei + e;

    char* ws = (char*)d_ws;
    size_t off = 0;
    auto alloc = [&](size_t bytes) -> void* {
        void* p = ws + off;
        off = (off + bytes + 255) & ~(size_t)255;
        return p;
    };
    unsigned*           hb     = (unsigned*)alloc((size_t)n * 128 * 2);   // xw2 (bf16 pairs)
    unsigned*           xwb    = (unsigned*)alloc((size_t)n * 128 * 2);   // xw1 / xw3
    // union: packed (800KB dense, dead after k_scan1) aliases meta (12.8MB,
    // first written by k_fill which is stream-ordered after k_scan1).
    void*               uni    =            alloc((size_t)e * 8);
    unsigned long long* packed = (unsigned long long*)uni;
    uint2*              meta   = (uint2*)uni;
    float*              dinv   = (float*)   alloc((size_t)n * 4);
    int*                rowptr = (int*)     alloc((size_t)(n + 1) * 4);
    int*                rank   = (int*)     alloc((size_t)e * 4);
    int*                part   = (int*)     alloc(512 * 4);
    ushort*             wt     = (ushort*)  alloc(6 * 16384 * 2);  // 3x {W^T hi, W^T lo}
    (void)ws_size; (void)in_sizes; (void)n_in; (void)out_size;

    int nb = (n + 255) / 256;   // 391
    int eb = (e + 255) / 256;   // 6250
    int gb = n / 32;            // 3125

    // fused zero-init + weight prep: 391 + 192 blocks
    k_pre<<<nb + 192, 256, 0, stream>>>(packed, n, W1, W2, W3, wt);

    k_gp<<<gb + eb, 256, 0, stream>>>(x, wt + 0 * 16384, wt + 1 * 16384, xwb, col, ew, packed, rank, e);
    k_scan1<<<nb, 256, 0, stream>>>(packed, rowptr, part, dinv, n);
    k_scan2<<<1, 512, 0, stream>>>(part, nb, rowptr, e);
    k_fill<<<eb, 256, 0, stream>>>(row, col, ew, rowptr, part, rank, dinv, meta, e);

    // layer-1 agg + relu + layer-2 GEMM  (xw1 -> xw2)
    k_aggemm<<<gb, 256, 0, stream>>>(xwb, rowptr, part, meta, dinv, b1,
                                     wt + 2 * 16384, wt + 3 * 16384, hb);
    // layer-2 agg + relu + layer-3 GEMM  (xw2 -> xw3)
    k_aggemm<<<gb, 256, 0, stream>>>(hb, rowptr, part, meta, dinv, b2,
                                     wt + 4 * 16384, wt + 5 * 16384, xwb);
    // layer-3 agg (fp32 out, no relu)
    k_agg<<<gb, 256, 0, stream>>>(xwb, rowptr, part, meta, dinv, b3, out);
}

// Round 10
// 475.456 us; speedup vs baseline: 1.0997x; 1.0997x over previous
//
#include <hip/hip_runtime.h>

#define NN 100000
#define NE 1600000

typedef __attribute__((ext_vector_type(8))) short short8;   // 8 bf16 = 4 VGPRs (MFMA A/B frag)
typedef __attribute__((ext_vector_type(4))) float f32x4;    // MFMA C/D frag

// bf16 helpers
static __device__ __forceinline__ unsigned f2bf_rne(float f) {
    unsigned u = __float_as_uint(f);
    return (u + 0x7FFFu + ((u >> 16) & 1u)) >> 16;   // round-to-nearest-even
}
static __device__ __forceinline__ float bf_lo(unsigned u) { return __uint_as_float(u << 16); }
static __device__ __forceinline__ float bf_hi(unsigned u) { return __uint_as_float(u & 0xFFFF0000u); }

// packed[]: DENSE u64 per node. count in bits 0..23, sum(ew*2^20) in 24..63.
// Aliases meta's storage (packed dead after k_scan; meta written by k_fill).
// fused: zero packed + zero lookback slots + 3x weight prep in one launch.
__global__ __launch_bounds__(256) void k_pre(unsigned long long* packed, int n,
                                             unsigned long long* lb,
                                             const float* __restrict__ W1,
                                             const float* __restrict__ W2,
                                             const float* __restrict__ W3,
                                             ushort* __restrict__ wt) {
    int b = blockIdx.x;
    int t = threadIdx.x;
    if (b < 391) {
        int i = b * 256 + t;
        if (i < n) packed[i] = 0ull;
        if (t == 0) lb[b] = 0ull;        // lookback slot for k_scan
        return;
    }
    int pb = b - 391;                    // 0..191
    int wsel = pb >> 6;                  // 0,1,2
    const float* W = (wsel == 0) ? W1 : (wsel == 1) ? W2 : W3;
    ushort* Wth = wt + wsel * 2 * 16384;
    ushort* Wtl = Wth + 16384;
    int idx = (pb & 63) * 256 + t;       // 0..16383
    int k = idx >> 7, nn = idx & 127;
    float w = W[idx];
    unsigned hi = f2bf_rne(w);
    unsigned lo = f2bf_rne(w - bf_lo(hi));   // residual: W ~= hi + lo to ~2^-17 rel
    Wth[nn * 128 + k] = (ushort)hi;
    Wtl[nn * 128 + k] = (ushort)lo;
}

// ---------------- MFMA GEMM core: 32 rows x 128 cols per block, 4 waves ----------------
template <bool SPLIT_A>
static __device__ __forceinline__ void mfma_tile(const ushort* sAh, const ushort* sAl,
                                                 const ushort* __restrict__ Wth,
                                                 const ushort* __restrict__ Wtl,
                                                 unsigned* __restrict__ Cb,
                                                 size_t r0, int t) {
    int w  = t >> 6;
    int l  = t & 63;
    int lr = l & 15;            // row idx within A-frag / col idx within B-frag
    int lk = (l >> 4) << 3;     // k offset 0,8,16,24 within the 32-wide k-step
    int n0 = w * 32;

    short8 bh[2][4], bl[2][4];
#pragma unroll
    for (int cf = 0; cf < 2; ++cf)
#pragma unroll
        for (int ks = 0; ks < 4; ++ks) {
            int n = n0 + cf * 16 + lr;
            bh[cf][ks] = *(const short8*)&Wth[n * 128 + ks * 32 + lk];
            bl[cf][ks] = *(const short8*)&Wtl[n * 128 + ks * 32 + lk];
        }

    f32x4 zero = {0.f, 0.f, 0.f, 0.f};
    f32x4 acc[2][2] = {{zero, zero}, {zero, zero}};

    __syncthreads();   // sA staging (done by caller) now visible

#pragma unroll
    for (int ks = 0; ks < 4; ++ks) {
        short8 ah[2], al[2];
#pragma unroll
        for (int rf = 0; rf < 2; ++rf) {
            int off = (rf * 16 + lr) * 136 + ks * 32 + lk;
            ah[rf] = *(const short8*)&sAh[off];
            if (SPLIT_A) al[rf] = *(const short8*)&sAl[off];
        }
#pragma unroll
        for (int rf = 0; rf < 2; ++rf)
#pragma unroll
            for (int cf = 0; cf < 2; ++cf) {
                acc[rf][cf] = __builtin_amdgcn_mfma_f32_16x16x32_bf16(ah[rf], bh[cf][ks], acc[rf][cf], 0, 0, 0);
                acc[rf][cf] = __builtin_amdgcn_mfma_f32_16x16x32_bf16(ah[rf], bl[cf][ks], acc[rf][cf], 0, 0, 0);
                if (SPLIT_A)
                    acc[rf][cf] = __builtin_amdgcn_mfma_f32_16x16x32_bf16(al[rf], bh[cf][ks], acc[rf][cf], 0, 0, 0);
            }
    }

    // C/D layout: col = l&15, row = (l>>4)*4 + reg. Pack bf16 col-pairs via shfl_xor(1).
#pragma unroll
    for (int rf = 0; rf < 2; ++rf)
#pragma unroll
        for (int cf = 0; cf < 2; ++cf)
#pragma unroll
            for (int r = 0; r < 4; ++r) {
                unsigned b = f2bf_rne(acc[rf][cf][r]);
                unsigned p = (unsigned)__shfl_xor((int)b, 1);
                if (!(l & 1)) {
                    size_t row = r0 + rf * 16 + ((l >> 4) << 2) + r;
                    int c = n0 + cf * 16 + lr;           // even
                    Cb[(row * 128 + c) >> 1] = b | (p << 16);
                }
            }
}

// ---------------- fused: layer-1 MFMA GEMM (fp32 A, split) || edge histogram ----------------
__global__ __launch_bounds__(256) void k_gp(const float* __restrict__ A,
                                            const ushort* __restrict__ Wth,
                                            const ushort* __restrict__ Wtl,
                                            unsigned* __restrict__ Cb,
                                            const int* __restrict__ col,
                                            const float* __restrict__ ew,
                                            unsigned long long* packed,
                                            int* __restrict__ rank, int e) {
    __shared__ alignas(16) ushort sAh[32 * 136];
    __shared__ alignas(16) ushort sAl[32 * 136];
    int b = blockIdx.x;
    int sub = b % 3;
    int q = b / 3;
    int t = threadIdx.x;

    if (sub != 0) {
        int p = q * 2 + sub - 1;            // 0..6249
        int i = p * 256 + t;
        if (i < e) {
            int c = col[i];
            unsigned fe = (unsigned)__float2uint_rn(ew[i] * 1048576.0f);  // 20 frac bits
            unsigned long long inc = ((unsigned long long)fe << 24) | 1ull;
            unsigned long long old = atomicAdd(&packed[c], inc);
            rank[i] = (int)(old & 0xFFFFFFull);
        }
        return;
    }

    size_t r0 = (size_t)q * 32;
    const float4* A4 = (const float4*)(A + r0 * 128);
#pragma unroll
    for (int i = 0; i < 4; ++i) {
        int j = t + 256 * i;                // float4 idx 0..1023
        float4 f = A4[j];
        int rr = j >> 5;
        int cc = (j & 31) << 2;
        unsigned h0 = f2bf_rne(f.x), h1 = f2bf_rne(f.y), h2 = f2bf_rne(f.z), h3 = f2bf_rne(f.w);
        unsigned g0 = f2bf_rne(f.x - bf_lo(h0)), g1 = f2bf_rne(f.y - bf_lo(h1));
        unsigned g2 = f2bf_rne(f.z - bf_lo(h2)), g3 = f2bf_rne(f.w - bf_lo(h3));
        *(ushort4*)&sAh[rr * 136 + cc] = make_ushort4((ushort)h0, (ushort)h1, (ushort)h2, (ushort)h3);
        *(ushort4*)&sAl[rr * 136 + cc] = make_ushort4((ushort)g0, (ushort)g1, (ushort)g2, (ushort)g3);
    }
    mfma_tile<true>(sAh, sAl, Wth, Wtl, Cb, r0, t);
}

// ---------------- single-pass scan: local scan + decoupled lookback -> FINAL rowptr ----------------
// 391 blocks, all trivially co-resident (tiny LDS/VGPR) so predecessor spin is safe.
// Cross-block words (lb[]) use agent-scope atomic load/store only (per-XCD L2s are
// not coherent for plain accesses). lb[b] = (1<<32) | block_sum. Also emits dinv.
__global__ __launch_bounds__(256) void k_scan(const unsigned long long* __restrict__ packed,
                                              int* __restrict__ rowptr,
                                              unsigned long long* lb,
                                              float* __restrict__ dinv, int n, int e) {
    __shared__ int s[256];
    int t = threadIdx.x, b = blockIdx.x;
    int i = b * 256 + t;
    unsigned long long pk = (i < n) ? packed[i] : 0ull;
    int v = (int)(pk & 0xFFFFFFull);
    if (i < n) {
        float deg = 1.0f + (float)(pk >> 24) * (1.0f / 1048576.0f);  // +1 self-loop
        dinv[i] = rsqrtf(deg);
    }
    s[t] = v;
    __syncthreads();
    for (int d = 1; d < 256; d <<= 1) {
        int y = (t >= d) ? s[t - d] : 0;
        __syncthreads();
        s[t] += y;
        __syncthreads();
    }
    int incl = s[t];
    if (t == 255)
        __hip_atomic_store(&lb[b], (1ull << 32) | (unsigned long long)(unsigned)s[255],
                           __ATOMIC_RELEASE, __HIP_MEMORY_SCOPE_AGENT);

    // lookback: sum all predecessor block sums (spin until each is published)
    int mysum = 0;
    for (int j = t; j < b; j += 256) {
        unsigned long long x;
        do {
            x = __hip_atomic_load(&lb[j], __ATOMIC_ACQUIRE, __HIP_MEMORY_SCOPE_AGENT);
        } while (!(x >> 32));
        mysum += (int)(x & 0xFFFFFFFFull);
    }
    __syncthreads();           // incl saved in reg; safe to reuse s[]
    s[t] = mysum;
    __syncthreads();
    for (int d = 128; d > 0; d >>= 1) {
        if (t < d) s[t] += s[t + d];
        __syncthreads();
    }
    int prefix = s[0];
    if (i < n) rowptr[i] = prefix + incl - v;     // final exclusive prefix
    if (b == 390 && t == 255) rowptr[n] = e;
}

// atomic-free CSR fill; (src, wn) packed -> one 8-byte scattered store per edge
__global__ __launch_bounds__(256) void k_fill(const int* __restrict__ row,
                                              const int* __restrict__ col,
                                              const float* __restrict__ ew,
                                              const int* __restrict__ rowptr,
                                              const int* __restrict__ rank,
                                              const float* __restrict__ dinv,
                                              uint2* __restrict__ meta, int e) {
    int i = blockIdx.x * 256 + threadIdx.x;
    if (i < e) {
        int c = col[i];
        int r = row[i];
        int p = rowptr[c] + rank[i];
        float w = dinv[r] * ew[i] * dinv[c];
        meta[p] = make_uint2((unsigned)r, __float_as_uint(w));
    }
}

// ---------------- DUAL-node aggregation core (4 nodes/wave, 2 per half-wave) ----------------
// Half-wave h owns nodes {nodeA, nodeB}; lane owns feature quad q (uint2 = 8B).
// Both nodes' chunk loops interleave -> 2x gathers in flight per half-wave.
// Each node's accumulation is strictly sequential in its CSR order per feature:
// bit-identical association to the verified r6/r7/r8 versions.
static __device__ __forceinline__ void agg_node2(const uint2* __restrict__ X2,
                                                 const int* __restrict__ rowptr,
                                                 const uint2* __restrict__ meta,
                                                 const float* __restrict__ dinv,
                                                 const float* __restrict__ bias,
                                                 int nodeA, int nodeB, int h, int q,
                                                 float* aA, float* aB) {
    float4 bv = *(const float4*)(bias + q * 4);
    float diA = dinv[nodeA], diB = dinv[nodeB];
    uint2 usA = X2[(size_t)nodeA * 32 + q];
    uint2 usB = X2[(size_t)nodeB * 32 + q];
    float swA = diA * diA, swB = diB * diB;
    aA[0] = fmaf(swA, bf_lo(usA.x), bv.x);  aA[1] = fmaf(swA, bf_hi(usA.x), bv.y);
    aA[2] = fmaf(swA, bf_lo(usA.y), bv.z);  aA[3] = fmaf(swA, bf_hi(usA.y), bv.w);
    aB[0] = fmaf(swB, bf_lo(usB.x), bv.x);  aB[1] = fmaf(swB, bf_hi(usB.x), bv.y);
    aB[2] = fmaf(swB, bf_lo(usB.y), bv.z);  aB[3] = fmaf(swB, bf_hi(usB.y), bv.w);

    int p0A = rowptr[nodeA], degA = rowptr[nodeA + 1] - p0A;
    int p0B = rowptr[nodeB], degB = rowptr[nodeB + 1] - p0B;
    int dloc = max(degA, degB);
    int dm = max(dloc, __shfl_xor(dloc, 32));   // wave-uniform chunk count

    for (int base = 0; base < dm; base += 32) {
        int mA = degA - base;  mA = mA > 32 ? 32 : mA;
        int mB = degB - base;  mB = mB > 32 ? 32 : mB;
        int mm = dm - base;    mm = mm > 32 ? 32 : mm;
        int idxA = p0A + base + (q < mA ? q : (mA > 0 ? mA - 1 : 0));
        if (mA <= 0) idxA = p0A;
        if (idxA > NE - 1) idxA = NE - 1;
        int idxB = p0B + base + (q < mB ? q : (mB > 0 ? mB - 1 : 0));
        if (mB <= 0) idxB = p0B;
        if (idxB > NE - 1) idxB = NE - 1;
        uint2 mvA = meta[idxA];
        uint2 mvB = meta[idxB];
        int svA = (int)mvA.x;  float wvA = __uint_as_float(mvA.y);
        int svB = (int)mvB.x;  float wvB = __uint_as_float(mvB.y);

        int j = 0;
        for (; j + 4 <= mm; j += 4) {
#pragma unroll
            for (int u = 0; u < 4; ++u) {
                int jj = j + u;
                int sA = __shfl(svA, (h << 5) | jj);
                int sB = __shfl(svB, (h << 5) | jj);
                float wA = __shfl(wvA, (h << 5) | jj);
                float wB = __shfl(wvB, (h << 5) | jj);
                wA = (jj < mA) ? wA : 0.0f;
                wB = (jj < mB) ? wB : 0.0f;
                uint2 uA = X2[(size_t)sA * 32 + q];
                uint2 uB = X2[(size_t)sB * 32 + q];
                aA[0] = fmaf(wA, bf_lo(uA.x), aA[0]);  aA[1] = fmaf(wA, bf_hi(uA.x), aA[1]);
                aA[2] = fmaf(wA, bf_lo(uA.y), aA[2]);  aA[3] = fmaf(wA, bf_hi(uA.y), aA[3]);
                aB[0] = fmaf(wB, bf_lo(uB.x), aB[0]);  aB[1] = fmaf(wB, bf_hi(uB.x), aB[1]);
                aB[2] = fmaf(wB, bf_lo(uB.y), aB[2]);  aB[3] = fmaf(wB, bf_hi(uB.y), aB[3]);
            }
        }
        for (; j < mm; ++j) {
            int sA = __shfl(svA, (h << 5) | j);
            int sB = __shfl(svB, (h << 5) | j);
            float wA = __shfl(wvA, (h << 5) | j);
            float wB = __shfl(wvB, (h << 5) | j);
            wA = (j < mA) ? wA : 0.0f;
            wB = (j < mB) ? wB : 0.0f;
            uint2 uA = X2[(size_t)sA * 32 + q];
            uint2 uB = X2[(size_t)sB * 32 + q];
            aA[0] = fmaf(wA, bf_lo(uA.x), aA[0]);  aA[1] = fmaf(wA, bf_hi(uA.x), aA[1]);
            aA[2] = fmaf(wA, bf_lo(uA.y), aA[2]);  aA[3] = fmaf(wA, bf_hi(uA.y), aA[3]);
            aB[0] = fmaf(wB, bf_lo(uB.x), aB[0]);  aB[1] = fmaf(wB, bf_hi(uB.x), aB[1]);
            aB[2] = fmaf(wB, bf_lo(uB.y), aB[2]);  aB[3] = fmaf(wB, bf_hi(uB.y), aB[3]);
        }
    }
}

// ---------------- fused: aggregation(layer L) + relu/bias + GEMM(layer L+1) ----------------
// Block owns 32 nodes: 4 waves x (2 passes x 2 halves x 2 nodes).
__global__ __launch_bounds__(256) void k_aggemm(const unsigned* __restrict__ Xsrc,
                                                const int* __restrict__ rowptr,
                                                const uint2* __restrict__ meta,
                                                const float* __restrict__ dinv,
                                                const float* __restrict__ bias,
                                                const ushort* __restrict__ Wth,
                                                const ushort* __restrict__ Wtl,
                                                unsigned* __restrict__ Cb) {
    __shared__ alignas(16) ushort sA[32 * 136];
    int t = threadIdx.x;
    int lane = t & 63, wid = t >> 6;
    int h = lane >> 5, q = lane & 31;
    const uint2* X2 = (const uint2*)Xsrc;
    size_t r0 = (size_t)blockIdx.x * 32;

#pragma unroll
    for (int p = 0; p < 2; ++p) {
        int ln = (p << 4) + (wid << 2) + (h << 1);   // 0,2,..,30 (+1 = partner)
        int nodeA = (int)r0 + ln;
        int nodeB = nodeA + 1;
        float aA[4], aB[4];
        agg_node2(X2, rowptr, meta, dinv, bias, nodeA, nodeB, h, q, aA, aB);
#pragma unroll
        for (int z = 0; z < 4; ++z) { aA[z] = fmaxf(aA[z], 0.0f); aB[z] = fmaxf(aB[z], 0.0f); }
        *(ushort4*)&sA[ln * 136 + (q << 2)] =
            make_ushort4((ushort)f2bf_rne(aA[0]), (ushort)f2bf_rne(aA[1]),
                         (ushort)f2bf_rne(aA[2]), (ushort)f2bf_rne(aA[3]));
        *(ushort4*)&sA[(ln + 1) * 136 + (q << 2)] =
            make_ushort4((ushort)f2bf_rne(aB[0]), (ushort)f2bf_rne(aB[1]),
                         (ushort)f2bf_rne(aB[2]), (ushort)f2bf_rne(aB[3]));
    }
    mfma_tile<false>(sA, nullptr, Wth, Wtl, Cb, r0, t);
}

// ---------------- standalone aggregation for layer 3 (fp32 out, no relu) ----------------
// Block covers 16 nodes (4 waves x 2 halves x 2 nodes); grid 6250.
__global__ __launch_bounds__(256) void k_agg(const unsigned* __restrict__ XWb,
                                             const int* __restrict__ rowptr,
                                             const uint2* __restrict__ meta,
                                             const float* __restrict__ dinv,
                                             const float* __restrict__ bias,
                                             float* __restrict__ outf, int n) {
    int t = threadIdx.x;
    int lane = t & 63, wid = t >> 6;
    int h = lane >> 5, q = lane & 31;
    int nodeA = blockIdx.x * 16 + (wid << 2) + (h << 1);
    int nodeB = nodeA + 1;
    if (nodeB >= n) return;   // n = 100000 = 6250*16: never taken
    float aA[4], aB[4];
    agg_node2((const uint2*)XWb, rowptr, meta, dinv, bias, nodeA, nodeB, h, q, aA, aB);
    *(float4*)(outf + (size_t)nodeA * 128 + q * 4) = make_float4(aA[0], aA[1], aA[2], aA[3]);
    *(float4*)(outf + (size_t)nodeB * 128 + q * 4) = make_float4(aB[0], aB[1], aB[2], aB[3]);
}

// ---------------- launcher ----------------
extern "C" void kernel_launch(void* const* d_in, const int* in_sizes, int n_in,
                              void* d_out, int out_size, void* d_ws, size_t ws_size,
                              hipStream_t stream) {
    const float* x  = (const float*)d_in[0];
    const int*   ei = (const int*)d_in[1];
    const float* ew = (const float*)d_in[2];
    const float* W1 = (const float*)d_in[3];
    const float* b1 = (const float*)d_in[4];
    const float* W2 = (const float*)d_in[5];
    const float* b2 = (const float*)d_in[6];
    const float* W3 = (const float*)d_in[7];
    const float* b3 = (const float*)d_in[8];
    float* out = (float*)d_out;

    const int n = NN, e = NE;
    const int* row = ei;
    const int* col = ei + e;

    char* ws = (char*)d_ws;
    size_t off = 0;
    auto alloc = [&](size_t bytes) -> void* {
        void* p = ws + off;
        off = (off + bytes + 255) & ~(size_t)255;
        return p;
    };
    unsigned*           hb     = (unsigned*)alloc((size_t)n * 128 * 2);   // xw2 (bf16 pairs)
    unsigned*           xwb    = (unsigned*)alloc((size_t)n * 128 * 2);   // xw1 / xw3
    // union: packed (800KB dense, dead after k_scan) aliases meta (12.8MB,
    // first written by k_fill which is stream-ordered after k_scan).
    void*               uni    =            alloc((size_t)e * 8);
    unsigned long long* packed = (unsigned long long*)uni;
    uint2*              meta   = (uint2*)uni;
    float*              dinv   = (float*)   alloc((size_t)n * 4);
    int*                rowptr = (int*)     alloc((size_t)(n + 1) * 4);
    int*                rank   = (int*)     alloc((size_t)e * 4);
    unsigned long long* lb     = (unsigned long long*)alloc(512 * 8);
    ushort*             wt     = (ushort*)  alloc(6 * 16384 * 2);  // 3x {W^T hi, W^T lo}
    (void)ws_size; (void)in_sizes; (void)n_in; (void)out_size;

    int nb = (n + 255) / 256;   // 391
    int eb = (e + 255) / 256;   // 6250
    int gb = n / 32;            // 3125

    // fused zero-init (packed + lb) + weight prep: 391 + 192 blocks
    k_pre<<<nb + 192, 256, 0, stream>>>(packed, n, lb, W1, W2, W3, wt);

    k_gp<<<gb + eb, 256, 0, stream>>>(x, wt + 0 * 16384, wt + 1 * 16384, xwb, col, ew, packed, rank, e);
    // single-pass scan (replaces scan1+scan2+scan3): final rowptr + dinv
    k_scan<<<nb, 256, 0, stream>>>(packed, rowptr, lb, dinv, n, e);
    k_fill<<<eb, 256, 0, stream>>>(row, col, ew, rowptr, rank, dinv, meta, e);

    // layer-1 agg + relu + layer-2 GEMM  (xw1 -> xw2)
    k_aggemm<<<gb, 256, 0, stream>>>(xwb, rowptr, meta, dinv, b1,
                                     wt + 2 * 16384, wt + 3 * 16384, hb);
    // layer-2 agg + relu + layer-3 GEMM  (xw2 -> xw3)
    k_aggemm<<<gb, 256, 0, stream>>>(hb, rowptr, meta, dinv, b2,
                                     wt + 4 * 16384, wt + 5 * 16384, xwb);
    // layer-3 agg (fp32 out, no relu)
    k_agg<<<6250, 256, 0, stream>>>(xwb, rowptr, meta, dinv, b3, out, n);
}

// Round 11
// 458.503 us; speedup vs baseline: 1.1404x; 1.0370x over previous
//
#include <hip/hip_runtime.h>

#define NN 100000
#define NE 1600000

typedef __attribute__((ext_vector_type(8))) short short8;   // 8 bf16 = 4 VGPRs (MFMA A/B frag)
typedef __attribute__((ext_vector_type(4))) float f32x4;    // MFMA C/D frag

// bf16 helpers
static __device__ __forceinline__ unsigned f2bf_rne(float f) {
    unsigned u = __float_as_uint(f);
    return (u + 0x7FFFu + ((u >> 16) & 1u)) >> 16;   // round-to-nearest-even
}
static __device__ __forceinline__ float bf_lo(unsigned u) { return __uint_as_float(u << 16); }
static __device__ __forceinline__ float bf_hi(unsigned u) { return __uint_as_float(u & 0xFFFF0000u); }

// packed[]: DENSE u64 per node. count in bits 0..23, sum(ew*2^20) in 24..63.
// Aliases meta's storage (packed dead after k_scan1; meta written by k_fill).
// fused: k_init (zero packed) + 3x k_prep (W -> W^T bf16 hi/lo) in one launch.
__global__ __launch_bounds__(256) void k_pre(unsigned long long* packed, int n,
                                             const float* __restrict__ W1,
                                             const float* __restrict__ W2,
                                             const float* __restrict__ W3,
                                             ushort* __restrict__ wt) {
    int b = blockIdx.x;
    int t = threadIdx.x;
    if (b < 391) {
        int i = b * 256 + t;
        if (i < n) packed[i] = 0ull;
        return;
    }
    int pb = b - 391;                    // 0..191
    int wsel = pb >> 6;                  // 0,1,2
    const float* W = (wsel == 0) ? W1 : (wsel == 1) ? W2 : W3;
    ushort* Wth = wt + wsel * 2 * 16384;
    ushort* Wtl = Wth + 16384;
    int idx = (pb & 63) * 256 + t;       // 0..16383
    int k = idx >> 7, nn = idx & 127;
    float w = W[idx];
    unsigned hi = f2bf_rne(w);
    unsigned lo = f2bf_rne(w - bf_lo(hi));   // residual: W ~= hi + lo to ~2^-17 rel
    Wth[nn * 128 + k] = (ushort)hi;
    Wtl[nn * 128 + k] = (ushort)lo;
}

// ---------------- MFMA GEMM core: 32 rows x 128 cols per block, 4 waves ----------------
// sched_barrier(0) at entry: prevents the machine scheduler from hoisting the
// 128-VGPR B-fragment loads above the caller's aggregation loop (which was
// inflating live registers across the gather phase -> ~2.8 blocks/CU occupancy).
template <bool SPLIT_A>
static __device__ __forceinline__ void mfma_tile(const ushort* sAh, const ushort* sAl,
                                                 const ushort* __restrict__ Wth,
                                                 const ushort* __restrict__ Wtl,
                                                 unsigned* __restrict__ Cb,
                                                 size_t r0, int t) {
    __builtin_amdgcn_sched_barrier(0);

    int w  = t >> 6;
    int l  = t & 63;
    int lr = l & 15;            // row idx within A-frag / col idx within B-frag
    int lk = (l >> 4) << 3;     // k offset 0,8,16,24 within the 32-wide k-step
    int n0 = w * 32;

    short8 bh[2][4], bl[2][4];
#pragma unroll
    for (int cf = 0; cf < 2; ++cf)
#pragma unroll
        for (int ks = 0; ks < 4; ++ks) {
            int n = n0 + cf * 16 + lr;
            bh[cf][ks] = *(const short8*)&Wth[n * 128 + ks * 32 + lk];
            bl[cf][ks] = *(const short8*)&Wtl[n * 128 + ks * 32 + lk];
        }

    f32x4 zero = {0.f, 0.f, 0.f, 0.f};
    f32x4 acc[2][2] = {{zero, zero}, {zero, zero}};

    __syncthreads();   // sA staging (done by caller) now visible

#pragma unroll
    for (int ks = 0; ks < 4; ++ks) {
        short8 ah[2], al[2];
#pragma unroll
        for (int rf = 0; rf < 2; ++rf) {
            int off = (rf * 16 + lr) * 136 + ks * 32 + lk;
            ah[rf] = *(const short8*)&sAh[off];
            if (SPLIT_A) al[rf] = *(const short8*)&sAl[off];
        }
#pragma unroll
        for (int rf = 0; rf < 2; ++rf)
#pragma unroll
            for (int cf = 0; cf < 2; ++cf) {
                acc[rf][cf] = __builtin_amdgcn_mfma_f32_16x16x32_bf16(ah[rf], bh[cf][ks], acc[rf][cf], 0, 0, 0);
                acc[rf][cf] = __builtin_amdgcn_mfma_f32_16x16x32_bf16(ah[rf], bl[cf][ks], acc[rf][cf], 0, 0, 0);
                if (SPLIT_A)
                    acc[rf][cf] = __builtin_amdgcn_mfma_f32_16x16x32_bf16(al[rf], bh[cf][ks], acc[rf][cf], 0, 0, 0);
            }
    }

    // C/D layout: col = l&15, row = (l>>4)*4 + reg. Pack bf16 col-pairs via shfl_xor(1).
#pragma unroll
    for (int rf = 0; rf < 2; ++rf)
#pragma unroll
        for (int cf = 0; cf < 2; ++cf)
#pragma unroll
            for (int r = 0; r < 4; ++r) {
                unsigned b = f2bf_rne(acc[rf][cf][r]);
                unsigned p = (unsigned)__shfl_xor((int)b, 1);
                if (!(l & 1)) {
                    size_t row = r0 + rf * 16 + ((l >> 4) << 2) + r;
                    int c = n0 + cf * 16 + lr;           // even
                    Cb[(row * 128 + c) >> 1] = b | (p << 16);
                }
            }
}

// ---------------- fused: layer-1 MFMA GEMM (fp32 A, split) || edge histogram ----------------
__global__ __launch_bounds__(256) void k_gp(const float* __restrict__ A,
                                            const ushort* __restrict__ Wth,
                                            const ushort* __restrict__ Wtl,
                                            unsigned* __restrict__ Cb,
                                            const int* __restrict__ col,
                                            const float* __restrict__ ew,
                                            unsigned long long* packed,
                                            int* __restrict__ rank, int e) {
    __shared__ alignas(16) ushort sAh[32 * 136];
    __shared__ alignas(16) ushort sAl[32 * 136];
    int b = blockIdx.x;
    int sub = b % 3;
    int q = b / 3;
    int t = threadIdx.x;

    if (sub != 0) {
        int p = q * 2 + sub - 1;            // 0..6249
        int i = p * 256 + t;
        if (i < e) {
            int c = col[i];
            unsigned fe = (unsigned)__float2uint_rn(ew[i] * 1048576.0f);  // 20 frac bits
            unsigned long long inc = ((unsigned long long)fe << 24) | 1ull;
            unsigned long long old = atomicAdd(&packed[c], inc);
            rank[i] = (int)(old & 0xFFFFFFull);
        }
        return;
    }

    size_t r0 = (size_t)q * 32;
    const float4* A4 = (const float4*)(A + r0 * 128);
#pragma unroll
    for (int i = 0; i < 4; ++i) {
        int j = t + 256 * i;                // float4 idx 0..1023
        float4 f = A4[j];
        int rr = j >> 5;
        int cc = (j & 31) << 2;
        unsigned h0 = f2bf_rne(f.x), h1 = f2bf_rne(f.y), h2 = f2bf_rne(f.z), h3 = f2bf_rne(f.w);
        unsigned g0 = f2bf_rne(f.x - bf_lo(h0)), g1 = f2bf_rne(f.y - bf_lo(h1));
        unsigned g2 = f2bf_rne(f.z - bf_lo(h2)), g3 = f2bf_rne(f.w - bf_lo(h3));
        *(ushort4*)&sAh[rr * 136 + cc] = make_ushort4((ushort)h0, (ushort)h1, (ushort)h2, (ushort)h3);
        *(ushort4*)&sAl[rr * 136 + cc] = make_ushort4((ushort)g0, (ushort)g1, (ushort)g2, (ushort)g3);
    }
    mfma_tile<true>(sAh, sAl, Wth, Wtl, Cb, r0, t);
}

// fused: exclusive scan of counts -> rowptr, plus dinv = rsqrt(deg)
__global__ __launch_bounds__(256) void k_scan1(const unsigned long long* __restrict__ packed,
                                               int* __restrict__ rowptr,
                                               int* __restrict__ part,
                                               float* __restrict__ dinv, int n) {
    __shared__ int s[256];
    int t = threadIdx.x;
    int i = blockIdx.x * 256 + t;
    unsigned long long pk = (i < n) ? packed[i] : 0ull;
    int v = (int)(pk & 0xFFFFFFull);
    if (i < n) {
        float deg = 1.0f + (float)(pk >> 24) * (1.0f / 1048576.0f);  // +1 self-loop
        dinv[i] = rsqrtf(deg);
    }
    s[t] = v;
    __syncthreads();
    for (int d = 1; d < 256; d <<= 1) {
        int y = (t >= d) ? s[t - d] : 0;
        __syncthreads();
        s[t] += y;
        __syncthreads();
    }
    if (i < n) rowptr[i] = s[t] - v;
    if (t == 255) part[blockIdx.x] = s[255];
}

__global__ __launch_bounds__(512) void k_scan2(int* part, int m) {
    __shared__ int s[512];
    int t = threadIdx.x;
    int v = (t < m) ? part[t] : 0;
    s[t] = v;
    __syncthreads();
    for (int d = 1; d < 512; d <<= 1) {
        int y = (t >= d) ? s[t - d] : 0;
        __syncthreads();
        s[t] += y;
        __syncthreads();
    }
    if (t < m) part[t] = s[t] - v;
}

__global__ __launch_bounds__(256) void k_scan3(int* rowptr, const int* __restrict__ part, int n, int e) {
    int i = blockIdx.x * 256 + threadIdx.x;
    if (i < n) rowptr[i] += part[blockIdx.x];
    if (i == 0) rowptr[n] = e;
}

// atomic-free CSR fill; (src, wn) packed -> one 8-byte scattered store per edge
__global__ __launch_bounds__(256) void k_fill(const int* __restrict__ row,
                                              const int* __restrict__ col,
                                              const float* __restrict__ ew,
                                              const int* __restrict__ rowptr,
                                              const int* __restrict__ rank,
                                              const float* __restrict__ dinv,
                                              uint2* __restrict__ meta, int e) {
    int i = blockIdx.x * 256 + threadIdx.x;
    if (i < e) {
        int c = col[i];
        int r = row[i];
        int p = rowptr[c] + rank[i];
        float w = dinv[r] * ew[i] * dinv[c];
        meta[p] = make_uint2((unsigned)r, __float_as_uint(w));
    }
}

// ---------------- DUAL-node aggregation core (4 nodes/wave, 2 per half-wave) ----------------
// Half-wave h owns nodes {nodeA, nodeB}; lane owns feature quad q (uint2 = 8B).
// Both nodes' chunk loops interleave -> 2x gathers in flight per half-wave.
// Each node's accumulation is strictly sequential in its CSR order per feature:
// bit-identical association to the verified r6/r7/r8 versions.
static __device__ __forceinline__ void agg_node2(const uint2* __restrict__ X2,
                                                 const int* __restrict__ rowptr,
                                                 const uint2* __restrict__ meta,
                                                 const float* __restrict__ dinv,
                                                 const float* __restrict__ bias,
                                                 int nodeA, int nodeB, int h, int q,
                                                 float* aA, float* aB) {
    float4 bv = *(const float4*)(bias + q * 4);
    float diA = dinv[nodeA], diB = dinv[nodeB];
    uint2 usA = X2[(size_t)nodeA * 32 + q];
    uint2 usB = X2[(size_t)nodeB * 32 + q];
    float swA = diA * diA, swB = diB * diB;
    aA[0] = fmaf(swA, bf_lo(usA.x), bv.x);  aA[1] = fmaf(swA, bf_hi(usA.x), bv.y);
    aA[2] = fmaf(swA, bf_lo(usA.y), bv.z);  aA[3] = fmaf(swA, bf_hi(usA.y), bv.w);
    aB[0] = fmaf(swB, bf_lo(usB.x), bv.x);  aB[1] = fmaf(swB, bf_hi(usB.x), bv.y);
    aB[2] = fmaf(swB, bf_lo(usB.y), bv.z);  aB[3] = fmaf(swB, bf_hi(usB.y), bv.w);

    int p0A = rowptr[nodeA], degA = rowptr[nodeA + 1] - p0A;
    int p0B = rowptr[nodeB], degB = rowptr[nodeB + 1] - p0B;
    int dloc = max(degA, degB);
    int dm = max(dloc, __shfl_xor(dloc, 32));   // wave-uniform chunk count

    for (int base = 0; base < dm; base += 32) {
        int mA = degA - base;  mA = mA > 32 ? 32 : mA;
        int mB = degB - base;  mB = mB > 32 ? 32 : mB;
        int mm = dm - base;    mm = mm > 32 ? 32 : mm;
        int idxA = p0A + base + (q < mA ? q : (mA > 0 ? mA - 1 : 0));
        if (mA <= 0) idxA = p0A;
        if (idxA > NE - 1) idxA = NE - 1;
        int idxB = p0B + base + (q < mB ? q : (mB > 0 ? mB - 1 : 0));
        if (mB <= 0) idxB = p0B;
        if (idxB > NE - 1) idxB = NE - 1;
        uint2 mvA = meta[idxA];
        uint2 mvB = meta[idxB];
        int svA = (int)mvA.x;  float wvA = __uint_as_float(mvA.y);
        int svB = (int)mvB.x;  float wvB = __uint_as_float(mvB.y);

        int j = 0;
        for (; j + 4 <= mm; j += 4) {
#pragma unroll
            for (int u = 0; u < 4; ++u) {
                int jj = j + u;
                int sA = __shfl(svA, (h << 5) | jj);
                int sB = __shfl(svB, (h << 5) | jj);
                float wA = __shfl(wvA, (h << 5) | jj);
                float wB = __shfl(wvB, (h << 5) | jj);
                wA = (jj < mA) ? wA : 0.0f;
                wB = (jj < mB) ? wB : 0.0f;
                uint2 uA = X2[(size_t)sA * 32 + q];
                uint2 uB = X2[(size_t)sB * 32 + q];
                aA[0] = fmaf(wA, bf_lo(uA.x), aA[0]);  aA[1] = fmaf(wA, bf_hi(uA.x), aA[1]);
                aA[2] = fmaf(wA, bf_lo(uA.y), aA[2]);  aA[3] = fmaf(wA, bf_hi(uA.y), aA[3]);
                aB[0] = fmaf(wB, bf_lo(uB.x), aB[0]);  aB[1] = fmaf(wB, bf_hi(uB.x), aB[1]);
                aB[2] = fmaf(wB, bf_lo(uB.y), aB[2]);  aB[3] = fmaf(wB, bf_hi(uB.y), aB[3]);
            }
        }
        for (; j < mm; ++j) {
            int sA = __shfl(svA, (h << 5) | j);
            int sB = __shfl(svB, (h << 5) | j);
            float wA = __shfl(wvA, (h << 5) | j);
            float wB = __shfl(wvB, (h << 5) | j);
            wA = (j < mA) ? wA : 0.0f;
            wB = (j < mB) ? wB : 0.0f;
            uint2 uA = X2[(size_t)sA * 32 + q];
            uint2 uB = X2[(size_t)sB * 32 + q];
            aA[0] = fmaf(wA, bf_lo(uA.x), aA[0]);  aA[1] = fmaf(wA, bf_hi(uA.x), aA[1]);
            aA[2] = fmaf(wA, bf_lo(uA.y), aA[2]);  aA[3] = fmaf(wA, bf_hi(uA.y), aA[3]);
            aB[0] = fmaf(wB, bf_lo(uB.x), aB[0]);  aB[1] = fmaf(wB, bf_hi(uB.x), aB[1]);
            aB[2] = fmaf(wB, bf_lo(uB.y), aB[2]);  aB[3] = fmaf(wB, bf_hi(uB.y), aB[3]);
        }
    }
}

// ---------------- fused: aggregation(layer L) + relu/bias + GEMM(layer L+1) ----------------
// Block owns 32 nodes: 4 waves x (2 passes x 2 halves x 2 nodes).
__global__ __launch_bounds__(256) void k_aggemm(const unsigned* __restrict__ Xsrc,
                                                const int* __restrict__ rowptr,
                                                const uint2* __restrict__ meta,
                                                const float* __restrict__ dinv,
                                                const float* __restrict__ bias,
                                                const ushort* __restrict__ Wth,
                                                const ushort* __restrict__ Wtl,
                                                unsigned* __restrict__ Cb) {
    __shared__ alignas(16) ushort sA[32 * 136];
    int t = threadIdx.x;
    int lane = t & 63, wid = t >> 6;
    int h = lane >> 5, q = lane & 31;
    const uint2* X2 = (const uint2*)Xsrc;
    size_t r0 = (size_t)blockIdx.x * 32;

#pragma unroll
    for (int p = 0; p < 2; ++p) {
        int ln = (p << 4) + (wid << 2) + (h << 1);   // 0,2,..,30 (+1 = partner)
        int nodeA = (int)r0 + ln;
        int nodeB = nodeA + 1;
        float aA[4], aB[4];
        agg_node2(X2, rowptr, meta, dinv, bias, nodeA, nodeB, h, q, aA, aB);
#pragma unroll
        for (int z = 0; z < 4; ++z) { aA[z] = fmaxf(aA[z], 0.0f); aB[z] = fmaxf(aB[z], 0.0f); }
        *(ushort4*)&sA[ln * 136 + (q << 2)] =
            make_ushort4((ushort)f2bf_rne(aA[0]), (ushort)f2bf_rne(aA[1]),
                         (ushort)f2bf_rne(aA[2]), (ushort)f2bf_rne(aA[3]));
        *(ushort4*)&sA[(ln + 1) * 136 + (q << 2)] =
            make_ushort4((ushort)f2bf_rne(aB[0]), (ushort)f2bf_rne(aB[1]),
                         (ushort)f2bf_rne(aB[2]), (ushort)f2bf_rne(aB[3]));
    }
    mfma_tile<false>(sA, nullptr, Wth, Wtl, Cb, r0, t);
}

// ---------------- standalone aggregation for layer 3 (fp32 out, no relu) ----------------
// Block covers 16 nodes (4 waves x 2 halves x 2 nodes); grid 6250.
__global__ __launch_bounds__(256) void k_agg(const unsigned* __restrict__ XWb,
                                             const int* __restrict__ rowptr,
                                             const uint2* __restrict__ meta,
                                             const float* __restrict__ dinv,
                                             const float* __restrict__ bias,
                                             float* __restrict__ outf, int n) {
    int t = threadIdx.x;
    int lane = t & 63, wid = t >> 6;
    int h = lane >> 5, q = lane & 31;
    int nodeA = blockIdx.x * 16 + (wid << 2) + (h << 1);
    int nodeB = nodeA + 1;
    if (nodeB >= n) return;   // n = 100000 = 6250*16: never taken
    float aA[4], aB[4];
    agg_node2((const uint2*)XWb, rowptr, meta, dinv, bias, nodeA, nodeB, h, q, aA, aB);
    *(float4*)(outf + (size_t)nodeA * 128 + q * 4) = make_float4(aA[0], aA[1], aA[2], aA[3]);
    *(float4*)(outf + (size_t)nodeB * 128 + q * 4) = make_float4(aB[0], aB[1], aB[2], aB[3]);
}

// ---------------- launcher ----------------
extern "C" void kernel_launch(void* const* d_in, const int* in_sizes, int n_in,
                              void* d_out, int out_size, void* d_ws, size_t ws_size,
                              hipStream_t stream) {
    const float* x  = (const float*)d_in[0];
    const int*   ei = (const int*)d_in[1];
    const float* ew = (const float*)d_in[2];
    const float* W1 = (const float*)d_in[3];
    const float* b1 = (const float*)d_in[4];
    const float* W2 = (const float*)d_in[5];
    const float* b2 = (const float*)d_in[6];
    const float* W3 = (const float*)d_in[7];
    const float* b3 = (const float*)d_in[8];
    float* out = (float*)d_out;

    const int n = NN, e = NE;
    const int* row = ei;
    const int* col = ei + e;

    char* ws = (char*)d_ws;
    size_t off = 0;
    auto alloc = [&](size_t bytes) -> void* {
        void* p = ws + off;
        off = (off + bytes + 255) & ~(size_t)255;
        return p;
    };
    unsigned*           hb     = (unsigned*)alloc((size_t)n * 128 * 2);   // xw2 (bf16 pairs)
    unsigned*           xwb    = (unsigned*)alloc((size_t)n * 128 * 2);   // xw1 / xw3
    // union: packed (800KB dense, dead after k_scan1) aliases meta (12.8MB,
    // first written by k_fill which is stream-ordered after k_scan1).
    void*               uni    =            alloc((size_t)e * 8);
    unsigned long long* packed = (unsigned long long*)uni;
    uint2*              meta   = (uint2*)uni;
    float*              dinv   = (float*)   alloc((size_t)n * 4);
    int*                rowptr = (int*)     alloc((size_t)(n + 1) * 4);
    int*                rank   = (int*)     alloc((size_t)e * 4);
    int*                part   = (int*)     alloc(512 * 4);
    ushort*             wt     = (ushort*)  alloc(6 * 16384 * 2);  // 3x {W^T hi, W^T lo}
    (void)ws_size; (void)in_sizes; (void)n_in; (void)out_size;

    int nb = (n + 255) / 256;   // 391
    int eb = (e + 255) / 256;   // 6250
    int gb = n / 32;            // 3125
    int ab = n / 16;            // 6250 (dual-node k_agg)

    // fused zero-init + weight prep: 391 + 192 blocks
    k_pre<<<nb + 192, 256, 0, stream>>>(packed, n, W1, W2, W3, wt);

    k_gp<<<gb + eb, 256, 0, stream>>>(x, wt + 0 * 16384, wt + 1 * 16384, xwb, col, ew, packed, rank, e);
    k_scan1<<<nb, 256, 0, stream>>>(packed, rowptr, part, dinv, n);
    k_scan2<<<1, 512, 0, stream>>>(part, nb);
    k_scan3<<<nb, 256, 0, stream>>>(rowptr, part, n, e);
    k_fill<<<eb, 256, 0, stream>>>(row, col, ew, rowptr, rank, dinv, meta, e);

    // layer-1 agg + relu + layer-2 GEMM  (xw1 -> xw2)
    k_aggemm<<<gb, 256, 0, stream>>>(xwb, rowptr, meta, dinv, b1,
                                     wt + 2 * 16384, wt + 3 * 16384, hb);
    // layer-2 agg + relu + layer-3 GEMM  (xw2 -> xw3)
    k_aggemm<<<gb, 256, 0, stream>>>(hb, rowptr, meta, dinv, b2,
                                     wt + 4 * 16384, wt + 5 * 16384, xwb);
    // layer-3 agg (fp32 out, no relu)
    k_agg<<<ab, 256, 0, stream>>>(xwb, rowptr, meta, dinv, b3, out, n);
}